// Round 1
// baseline (805.186 us; speedup 1.0000x reference)
//
#include <hip/hip_runtime.h>
#include <hip/hip_bf16.h>

// out[M,N] = X[M,K] @ W[K,N] + (X@A[K,16])@B[16,N] + bias[N]
// M=16384 (B*S), N=K=4096. Strategy:
//   P1: cast X fp32 -> bf16 (Xb)
//   P2: Wt[n][k] = bf16(W[k][n] + sum_r A[k][r]*B[r][n])   (LoRA folded, transposed)
//   G : 128x128-tile bf16 MFMA GEMM (m97 structure), fp32 accum, bias epilogue.

typedef __attribute__((ext_vector_type(8))) __bf16 bf16x8;
typedef __attribute__((ext_vector_type(4))) float f32x4;

#define M_DIM 16384
#define N_DIM 4096
#define K_DIM 4096

__device__ __forceinline__ void async16(const void* g, void* l) {
    __builtin_amdgcn_global_load_lds((const __attribute__((address_space(1))) void*)g,
                                     (__attribute__((address_space(3))) void*)l,
                                     16, 0, 0);
}

// ---------------- P1: cast X to bf16 ----------------
__global__ void cast_x_kernel(const float* __restrict__ x, __bf16* __restrict__ xb, size_t n) {
    size_t i0 = ((size_t)blockIdx.x * blockDim.x + threadIdx.x) * 8;
    size_t stride = (size_t)gridDim.x * blockDim.x * 8;
    for (size_t i = i0; i < n; i += stride) {
        float4 v0 = *(const float4*)(x + i);
        float4 v1 = *(const float4*)(x + i + 4);
        bf16x8 o;
        o[0] = (__bf16)v0.x; o[1] = (__bf16)v0.y; o[2] = (__bf16)v0.z; o[3] = (__bf16)v0.w;
        o[4] = (__bf16)v1.x; o[5] = (__bf16)v1.y; o[6] = (__bf16)v1.z; o[7] = (__bf16)v1.w;
        *(bf16x8*)(xb + i) = o;
    }
}

// ---------------- P2: Wt[n][k] = bf16(W[k][n] + lora) ----------------
// block (32,8), each block does a 32(k) x 32(n) tile of W.
__global__ void prep_w_kernel(const float* __restrict__ W, const float* __restrict__ A,
                              const float* __restrict__ Bm, __bf16* __restrict__ Wt) {
    __shared__ float Ws[32][33];
    __shared__ float As[32][16];
    __shared__ float Bs[16][32];
    const int tx = threadIdx.x;            // 0..31
    const int ty = threadIdx.y;            // 0..7
    const int t = ty * 32 + tx;            // 0..255
    const int n0 = blockIdx.x * 32;
    const int k0 = blockIdx.y * 32;

#pragma unroll
    for (int i = 0; i < 4; ++i) {
        int k = ty + i * 8;
        Ws[k][tx] = W[(size_t)(k0 + k) * N_DIM + n0 + tx];
    }
    for (int i = t; i < 512; i += 256) {
        As[i >> 4][i & 15] = A[(size_t)(k0 + (i >> 4)) * 16 + (i & 15)];
    }
    for (int i = t; i < 512; i += 256) {
        Bs[i >> 5][i & 31] = Bm[(size_t)(i >> 5) * N_DIM + n0 + (i & 31)];
    }
    __syncthreads();

    float a[16];
#pragma unroll
    for (int r = 0; r < 16; ++r) a[r] = As[tx][r];
#pragma unroll
    for (int i = 0; i < 4; ++i) {
        int n = ty + i * 8;
        float acc = Ws[tx][n];
#pragma unroll
        for (int r = 0; r < 16; ++r) acc += a[r] * Bs[r][n];
        Wt[(size_t)(n0 + n) * K_DIM + k0 + tx] = (__bf16)acc;
    }
}

// ---------------- G: 128x128 bf16 MFMA GEMM ----------------
// Xb: [M][K] bf16, Wt: [N][K] bf16 (i.e. W'^T), out: [M][N] fp32.
// 256 threads = 4 waves in 2x2; each wave owns 64x64 = 4x4 fragments of 16x16.
__global__ __launch_bounds__(256) void gemm_kernel(
    const __bf16* __restrict__ Xb, const __bf16* __restrict__ Wt,
    const float* __restrict__ bias, float* __restrict__ out) {
    __shared__ __align__(16) __bf16 As[128 * 32];
    __shared__ __align__(16) __bf16 Bs[128 * 32];

    const int tid  = threadIdx.x;
    const int lane = tid & 63;
    const int wave = tid >> 6;
    const int wr = wave >> 1;   // 0..1 (row half)
    const int wc = wave & 1;    // 0..1 (col half)
    const int m0 = blockIdx.y * 128;
    const int n0 = blockIdx.x * 128;

    f32x4 acc[4][4] = {};

    // staging geometry: chunk c (0..7) covers 16 rows of a [128][32] bf16 tile (1024B).
    // lane i in a chunk: row = 16c + (i>>2), k-offset = (i&3)*8 elements (16B load).
    const int r_in_chunk = lane >> 2;
    const int kk8 = (lane & 3) * 8;

    // fragment read geometry
    const int arow = wr * 64 + (lane & 15);
    const int brow = wc * 64 + (lane & 15);
    const int kh = (lane >> 4) * 8;

    for (int kt = 0; kt < K_DIM; kt += 32) {
#pragma unroll
        for (int cc = 0; cc < 2; ++cc) {
            const int c = wave * 2 + cc;
            const __bf16* ga = Xb + (size_t)(m0 + c * 16 + r_in_chunk) * K_DIM + kt + kk8;
            async16(ga, &As[c * 512]);
            const __bf16* gb = Wt + (size_t)(n0 + c * 16 + r_in_chunk) * K_DIM + kt + kk8;
            async16(gb, &Bs[c * 512]);
        }
        __syncthreads();   // drains vmcnt before barrier (compiler-inserted)

        bf16x8 af[4], bfr[4];
#pragma unroll
        for (int m = 0; m < 4; ++m)
            af[m] = *(const bf16x8*)&As[(arow + m * 16) * 32 + kh];
#pragma unroll
        for (int n = 0; n < 4; ++n)
            bfr[n] = *(const bf16x8*)&Bs[(brow + n * 16) * 32 + kh];

#pragma unroll
        for (int m = 0; m < 4; ++m)
#pragma unroll
            for (int n = 0; n < 4; ++n)
                acc[m][n] = __builtin_amdgcn_mfma_f32_16x16x32_bf16(af[m], bfr[n], acc[m][n], 0, 0, 0);
        __syncthreads();
    }

    // epilogue: C/D layout col = lane&15, row = (lane>>4)*4 + j  [m89-verified]
    const int rb = m0 + wr * 64 + (lane >> 4) * 4;
    const int cb = n0 + wc * 64 + (lane & 15);
#pragma unroll
    for (int n = 0; n < 4; ++n) {
        const int col = cb + n * 16;
        const float bv = bias[col];
#pragma unroll
        for (int m = 0; m < 4; ++m) {
#pragma unroll
            for (int j = 0; j < 4; ++j) {
                out[(size_t)(rb + m * 16 + j) * N_DIM + col] = acc[m][n][j] + bv;
            }
        }
    }
}

extern "C" void kernel_launch(void* const* d_in, const int* in_sizes, int n_in,
                              void* d_out, int out_size, void* d_ws, size_t ws_size,
                              hipStream_t stream) {
    const float* x    = (const float*)d_in[0];
    const float* W    = (const float*)d_in[1];
    const float* bias = (const float*)d_in[2];
    const float* lA   = (const float*)d_in[3];
    const float* lB   = (const float*)d_in[4];
    float* out = (float*)d_out;

    __bf16* Xb = (__bf16*)d_ws;                                   // 134,217,728 B
    __bf16* Wt = (__bf16*)((char*)d_ws + (size_t)M_DIM * K_DIM * 2); // + 33,554,432 B

    cast_x_kernel<<<2048, 256, 0, stream>>>(x, Xb, (size_t)M_DIM * K_DIM);
    prep_w_kernel<<<dim3(N_DIM / 32, K_DIM / 32), dim3(32, 8), 0, stream>>>(W, lA, lB, Wt);
    gemm_kernel<<<dim3(N_DIM / 128, M_DIM / 128), 256, 0, stream>>>(Xb, Wt, bias, out);
}

// Round 2
// 600.696 us; speedup vs baseline: 1.3404x; 1.3404x over previous
//
#include <hip/hip_runtime.h>
#include <hip/hip_bf16.h>

// out[M,N] = X[M,K] @ W[K,N] + (X@A)@B + bias;  M=16384, N=K=4096.
// P1: X -> bf16.  P2: Wt[n][k] = bf16(W[k][n] + lora).  G: 256x256 8-phase MFMA GEMM.

typedef __attribute__((ext_vector_type(8))) __bf16 bf16x8;
typedef __attribute__((ext_vector_type(4))) float f32x4;

#define M_DIM 16384
#define N_DIM 4096
#define K_DIM 4096

__device__ __forceinline__ void async16(const void* g, void* l) {
    __builtin_amdgcn_global_load_lds((const __attribute__((address_space(1))) void*)g,
                                     (__attribute__((address_space(3))) void*)l,
                                     16, 0, 0);
}

// ---------------- P1: cast X to bf16 ----------------
__global__ void cast_x_kernel(const float* __restrict__ x, __bf16* __restrict__ xb, size_t n) {
    size_t i0 = ((size_t)blockIdx.x * blockDim.x + threadIdx.x) * 8;
    size_t stride = (size_t)gridDim.x * blockDim.x * 8;
    for (size_t i = i0; i < n; i += stride) {
        float4 v0 = *(const float4*)(x + i);
        float4 v1 = *(const float4*)(x + i + 4);
        bf16x8 o;
        o[0] = (__bf16)v0.x; o[1] = (__bf16)v0.y; o[2] = (__bf16)v0.z; o[3] = (__bf16)v0.w;
        o[4] = (__bf16)v1.x; o[5] = (__bf16)v1.y; o[6] = (__bf16)v1.z; o[7] = (__bf16)v1.w;
        *(bf16x8*)(xb + i) = o;
    }
}

// ---------------- P2: Wt[n][k] = bf16(W[k][n] + lora) ----------------
__global__ void prep_w_kernel(const float* __restrict__ W, const float* __restrict__ A,
                              const float* __restrict__ Bm, __bf16* __restrict__ Wt) {
    __shared__ float Ws[32][33];
    __shared__ float As[32][16];
    __shared__ float Bs[16][32];
    const int tx = threadIdx.x;
    const int ty = threadIdx.y;
    const int t = ty * 32 + tx;
    const int n0 = blockIdx.x * 32;
    const int k0 = blockIdx.y * 32;

#pragma unroll
    for (int i = 0; i < 4; ++i) {
        int k = ty + i * 8;
        Ws[k][tx] = W[(size_t)(k0 + k) * N_DIM + n0 + tx];
    }
    for (int i = t; i < 512; i += 256)
        As[i >> 4][i & 15] = A[(size_t)(k0 + (i >> 4)) * 16 + (i & 15)];
    for (int i = t; i < 512; i += 256)
        Bs[i >> 5][i & 31] = Bm[(size_t)(i >> 5) * N_DIM + n0 + (i & 31)];
    __syncthreads();

    float a[16];
#pragma unroll
    for (int r = 0; r < 16; ++r) a[r] = As[tx][r];
#pragma unroll
    for (int i = 0; i < 4; ++i) {
        int n = ty + i * 8;
        float acc = Ws[tx][n];
#pragma unroll
        for (int r = 0; r < 16; ++r) acc += a[r] * Bs[r][n];
        Wt[(size_t)(n0 + n) * K_DIM + k0 + tx] = (__bf16)acc;
    }
}

// ---------------- G: 256x256 8-phase bf16 MFMA GEMM ----------------
// 512 threads = 8 waves (2 wr x 4 wn). Per wave 128x64 out = 8x4 frags of 16x16.
// LDS: 2 bufs x (A[256][64] + B[256][64]) bf16 = 128 KiB. BK=64, 2 K-tiles/iter.
// LDS col-swizzle: logical col c of row r stored at c ^ ((r&7)<<3)  (T2 recipe).
// B rows stored nh-permuted: phys p = nh*128 + wn*32 + s <-> logical n = wn*64+nh*32+s.
// Stage slots: q1: B-HT0(t+1), q2: A-HT1(t+1), q3: A-HT0(t+2), q4: B-HT1(t+2)+vmcnt(4).

#define WAIT_VM(N) asm volatile("s_waitcnt vmcnt(" #N ")" ::: "memory")
#define BARRIER() do { asm volatile("" ::: "memory"); __builtin_amdgcn_s_barrier(); asm volatile("" ::: "memory"); } while (0)

#define STAGE_A(ldsbase, row0, kt) do {                                              \
    int r_ = (row0) + srow;                                                          \
    async16(Xb + (size_t)(m0 + r_) * K_DIM + (kt) + scol,                            \
            (ldsbase) + (row0) * 128 + sldsoff); } while (0)

#define STAGE_B(ldsbase, row0, kt) do {                                              \
    int p_ = (row0) + srow;                                                          \
    int nl_ = ((p_ >> 5) & 3) * 64 + ((p_ >> 7) & 1) * 32 + (p_ & 31);               \
    async16(Wt + (size_t)(n0 + nl_) * K_DIM + (kt) + scol,                           \
            (ldsbase) + (row0) * 128 + sldsoff); } while (0)

#define LOAD_AF(ldsbase, MH)                                                         \
    _Pragma("unroll") for (int m_ = 0; m_ < 4; ++m_)                                 \
    _Pragma("unroll") for (int ks_ = 0; ks_ < 2; ++ks_)                              \
        afr[m_][ks_] = *(const bf16x8*)((ldsbase) + aRowB + (MH) * 8192 + m_ * 2048 + colsw[ks_]);

#define LOAD_BF(dst, ldsbase, NH)                                                    \
    _Pragma("unroll") for (int n_ = 0; n_ < 2; ++n_)                                 \
    _Pragma("unroll") for (int ks_ = 0; ks_ < 2; ++ks_)                              \
        dst[n_][ks_] = *(const bf16x8*)((ldsbase) + bRowB + (NH) * 16384 + n_ * 2048 + colsw[ks_]);

#define MFMA_Q(MH, NH, BF)                                                           \
    __builtin_amdgcn_s_setprio(1);                                                   \
    _Pragma("unroll") for (int m_ = 0; m_ < 4; ++m_)                                 \
    _Pragma("unroll") for (int n_ = 0; n_ < 2; ++n_)                                 \
    _Pragma("unroll") for (int ks_ = 0; ks_ < 2; ++ks_)                              \
        acc[(MH) * 4 + m_][(NH) * 2 + n_] = __builtin_amdgcn_mfma_f32_16x16x32_bf16( \
            afr[m_][ks_], BF[n_][ks_], acc[(MH) * 4 + m_][(NH) * 2 + n_], 0, 0, 0);  \
    __builtin_amdgcn_s_setprio(0);                                                   \
    __builtin_amdgcn_sched_barrier(0);

#define TILE_FULL(AC, BC, AO, BO, KT)                                                \
    LOAD_AF(AC, 0); LOAD_BF(b0f, BC, 0);                                             \
    STAGE_B(BO, 0, (KT) + 64); STAGE_B(BO, 64, (KT) + 64);                           \
    BARRIER(); MFMA_Q(0, 0, b0f); BARRIER();                                         \
    LOAD_BF(b1f, BC, 1);                                                             \
    STAGE_A(AO, 64, (KT) + 64); STAGE_A(AO, 192, (KT) + 64);                         \
    BARRIER(); MFMA_Q(0, 1, b1f); BARRIER();                                         \
    LOAD_AF(AC, 1);                                                                  \
    STAGE_A(AC, 0, (KT) + 128); STAGE_A(AC, 128, (KT) + 128);                        \
    BARRIER(); MFMA_Q(1, 1, b1f); BARRIER();                                         \
    STAGE_B(BC, 128, (KT) + 128); STAGE_B(BC, 192, (KT) + 128);                      \
    WAIT_VM(4);                                                                      \
    BARRIER(); MFMA_Q(1, 0, b0f); BARRIER();

__global__ __launch_bounds__(512, 2) void gemm256_kernel(
    const __bf16* __restrict__ Xb, const __bf16* __restrict__ Wt,
    const float* __restrict__ bias, float* __restrict__ out) {
    extern __shared__ __align__(16) char smem[];
    const int tid  = threadIdx.x;
    const int lane = tid & 63;
    const int wave = tid >> 6;
    const int wr = wave >> 2;   // 0..1
    const int wn = wave & 3;    // 0..3

    const int bid = blockIdx.x;
    const int wg = (bid & 7) * 128 + (bid >> 3);   // XCD swizzle, 1024 % 8 == 0
    const int m0 = (wg >> 4) * 256;
    const int n0 = (wg & 15) * 256;

    char* A0 = smem;
    char* B0 = smem + 32768;
    char* A1 = smem + 65536;
    char* B1 = smem + 98304;

    // staging constants: thread covers chunk row srow, 16B group (tid&7)
    const int srow = tid >> 3;
    const int scol = ((tid & 7) ^ (srow & 7)) << 3;   // inverse-swizzled source col (elems)
    const int sldsoff = wave * 1024;                  // wave-uniform LDS offset in chunk

    // frag-read constants (row&7 == lane&7 for all frag rows)
    int colsw[2];
#pragma unroll
    for (int ks = 0; ks < 2; ++ks)
        colsw[ks] = ((ks * 32 + (lane >> 4) * 8) ^ ((lane & 7) * 8)) << 1;
    const int aRowB = (wr * 128 + (lane & 15)) * 128;
    const int bRowB = (wn * 32 + (lane & 15)) * 128;

    f32x4 acc[8][4] = {};
    bf16x8 afr[4][2], b0f[2][2], b1f[2][2];

    // ---- prologue: tile0 (4 HTs) + tile1 {A-HT0, B-HT1}; leave last 4 loads in flight
    STAGE_A(A0, 0, 0);    STAGE_A(A0, 128, 0);
    STAGE_B(B0, 0, 0);    STAGE_B(B0, 64, 0);
    STAGE_A(A0, 64, 0);   STAGE_A(A0, 192, 0);
    STAGE_B(B0, 128, 0);  STAGE_B(B0, 192, 0);
    STAGE_A(A1, 0, 64);   STAGE_A(A1, 128, 64);
    STAGE_B(B1, 128, 64); STAGE_B(B1, 192, 64);
    WAIT_VM(4);
    BARRIER();

    // ---- main loop: tiles 0..61 (stages reference tiles up to 63)
    for (int it = 0; it < 31; ++it) {
        const int kt = it * 128;
        TILE_FULL(A0, B0, A1, B1, kt);
        TILE_FULL(A1, B1, A0, B0, kt + 64);
    }

    // ---- tile 62 (buf0, kt=3968): stage only tile63's B-HT0 / A-HT1; drain to 0
    LOAD_AF(A0, 0); LOAD_BF(b0f, B0, 0);
    STAGE_B(B1, 0, 4032); STAGE_B(B1, 64, 4032);
    BARRIER(); MFMA_Q(0, 0, b0f); BARRIER();
    LOAD_BF(b1f, B0, 1);
    STAGE_A(A1, 64, 4032); STAGE_A(A1, 192, 4032);
    BARRIER(); MFMA_Q(0, 1, b1f); BARRIER();
    LOAD_AF(A0, 1);
    BARRIER(); MFMA_Q(1, 1, b1f); BARRIER();
    WAIT_VM(0);
    BARRIER(); MFMA_Q(1, 0, b0f); BARRIER();

    // ---- tile 63 (buf1, kt=4032): no stages, no waits
    LOAD_AF(A1, 0); LOAD_BF(b0f, B1, 0);
    BARRIER(); MFMA_Q(0, 0, b0f); BARRIER();
    LOAD_BF(b1f, B1, 1);
    BARRIER(); MFMA_Q(0, 1, b1f); BARRIER();
    LOAD_AF(A1, 1);
    BARRIER(); MFMA_Q(1, 1, b1f); BARRIER();
    MFMA_Q(1, 0, b0f);

    // ---- epilogue: C/D map col=lane&15, row=(lane>>4)*4+j
#pragma unroll
    for (int mh = 0; mh < 2; ++mh)
#pragma unroll
        for (int m = 0; m < 4; ++m) {
            const int gr = m0 + wr * 128 + mh * 64 + m * 16 + (lane >> 4) * 4;
#pragma unroll
            for (int nh = 0; nh < 2; ++nh)
#pragma unroll
                for (int n = 0; n < 2; ++n) {
                    const int gc = n0 + wn * 64 + nh * 32 + n * 16 + (lane & 15);
                    const float bv = bias[gc];
                    const f32x4 a = acc[mh * 4 + m][nh * 2 + n];
#pragma unroll
                    for (int j = 0; j < 4; ++j)
                        out[(size_t)(gr + j) * N_DIM + gc] = a[j] + bv;
                }
        }
}

extern "C" void kernel_launch(void* const* d_in, const int* in_sizes, int n_in,
                              void* d_out, int out_size, void* d_ws, size_t ws_size,
                              hipStream_t stream) {
    const float* x    = (const float*)d_in[0];
    const float* W    = (const float*)d_in[1];
    const float* bias = (const float*)d_in[2];
    const float* lA   = (const float*)d_in[3];
    const float* lB   = (const float*)d_in[4];
    float* out = (float*)d_out;

    __bf16* Xb = (__bf16*)d_ws;
    __bf16* Wt = (__bf16*)((char*)d_ws + (size_t)M_DIM * K_DIM * 2);

    cast_x_kernel<<<2048, 256, 0, stream>>>(x, Xb, (size_t)M_DIM * K_DIM);
    prep_w_kernel<<<dim3(N_DIM / 32, K_DIM / 32), dim3(32, 8), 0, stream>>>(W, lA, lB, Wt);

    (void)hipFuncSetAttribute((const void*)gemm256_kernel,
                              hipFuncAttributeMaxDynamicSharedMemorySize, 131072);
    gemm256_kernel<<<1024, 512, 131072, stream>>>(Xb, Wt, bias, out);
}

// Round 4
// 576.650 us; speedup vs baseline: 1.3963x; 1.0417x over previous
//
#include <hip/hip_runtime.h>
#include <hip/hip_bf16.h>

// out[M,N] = X[M,K] @ W[K,N] + (X@A)@B + bias;  M=16384, N=K=4096.
// P1: X -> bf16.  P2: Wt[n][k] = bf16(W[k][n] + lora).  G: 256x256 8-phase MFMA GEMM.

typedef __attribute__((ext_vector_type(8))) __bf16 bf16x8;
typedef __attribute__((ext_vector_type(4))) float f32x4;

#define M_DIM 16384
#define N_DIM 4096
#define K_DIM 4096

__device__ __forceinline__ void async16(const void* g, void* l) {
    __builtin_amdgcn_global_load_lds((const __attribute__((address_space(1))) void*)g,
                                     (__attribute__((address_space(3))) void*)l,
                                     16, 0, 0);
}

// ---------------- P1: cast X to bf16 ----------------
__global__ void cast_x_kernel(const float* __restrict__ x, __bf16* __restrict__ xb, size_t n) {
    size_t i0 = ((size_t)blockIdx.x * blockDim.x + threadIdx.x) * 8;
    size_t stride = (size_t)gridDim.x * blockDim.x * 8;
    for (size_t i = i0; i < n; i += stride) {
        f32x4 v0 = __builtin_nontemporal_load((const f32x4*)(x + i));
        f32x4 v1 = __builtin_nontemporal_load((const f32x4*)(x + i + 4));
        bf16x8 o;
        o[0] = (__bf16)v0[0]; o[1] = (__bf16)v0[1]; o[2] = (__bf16)v0[2]; o[3] = (__bf16)v0[3];
        o[4] = (__bf16)v1[0]; o[5] = (__bf16)v1[1]; o[6] = (__bf16)v1[2]; o[7] = (__bf16)v1[3];
        *(bf16x8*)(xb + i) = o;
    }
}

// ---------------- P2: Wt[n][k] = bf16(W[k][n] + lora) ----------------
__global__ void prep_w_kernel(const float* __restrict__ W, const float* __restrict__ A,
                              const float* __restrict__ Bm, __bf16* __restrict__ Wt) {
    __shared__ float Ws[32][33];
    __shared__ float As[32][16];
    __shared__ float Bs[16][32];
    const int tx = threadIdx.x;
    const int ty = threadIdx.y;
    const int t = ty * 32 + tx;
    const int n0 = blockIdx.x * 32;
    const int k0 = blockIdx.y * 32;

#pragma unroll
    for (int i = 0; i < 4; ++i) {
        int k = ty + i * 8;
        Ws[k][tx] = W[(size_t)(k0 + k) * N_DIM + n0 + tx];
    }
    for (int i = t; i < 512; i += 256)
        As[i >> 4][i & 15] = A[(size_t)(k0 + (i >> 4)) * 16 + (i & 15)];
    for (int i = t; i < 512; i += 256)
        Bs[i >> 5][i & 31] = Bm[(size_t)(i >> 5) * N_DIM + n0 + (i & 31)];
    __syncthreads();

    float a[16];
#pragma unroll
    for (int r = 0; r < 16; ++r) a[r] = As[tx][r];
#pragma unroll
    for (int i = 0; i < 4; ++i) {
        int n = ty + i * 8;
        float acc = Ws[tx][n];
#pragma unroll
        for (int r = 0; r < 16; ++r) acc += a[r] * Bs[r][n];
        Wt[(size_t)(n0 + n) * K_DIM + k0 + tx] = (__bf16)acc;
    }
}

// ---------------- G: 256x256 8-phase bf16 MFMA GEMM ----------------
// 512 threads = 8 waves (2 wr x 4 wn). Per wave 128x64 out = 8x4 frags of 16x16.
// LDS: 2 bufs x (A[256][64] + B[256][64]) bf16 = 128 KiB. BK=64, 2 K-tiles/iter.
// LDS col-swizzle: logical col c of row r stored at c ^ ((r&7)<<3)  (T2 recipe).
// B rows stored nh-permuted: phys p = nh*128 + wn*32 + s <-> logical n = wn*64+nh*32+s.
// Stage slots: q1: B-HT0(t+1), q2: A-HT1(t+1), q3: A-HT0(t+2), q4: B-HT1(t+2).
// Wait ledger (per-load FIFO, 2 loads/slot):
//   end-q2(t): vmcnt(8)  -> drains q2(t-1)          [guards q3(t)'s A-MH1 reads, 4-phase flight]
//   end-q4(t): vmcnt(6)  -> drains q3(t-1),q4(t-1),q1(t)  [guards q1/q2(t+1), 3-phase flight]

#define WAIT_VM(N) asm volatile("s_waitcnt vmcnt(" #N ")" ::: "memory")
#define BARRIER() do { asm volatile("" ::: "memory"); __builtin_amdgcn_s_barrier(); asm volatile("" ::: "memory"); } while (0)

#define STAGE_A(ldsbase, row0, kt) do {                                              \
    int r_ = (row0) + srow;                                                          \
    async16(Xb + (size_t)(m0 + r_) * K_DIM + (kt) + scol,                            \
            (ldsbase) + (row0) * 128 + sldsoff); } while (0)

#define STAGE_B(ldsbase, row0, kt) do {                                              \
    int p_ = (row0) + srow;                                                          \
    int nl_ = ((p_ >> 5) & 3) * 64 + ((p_ >> 7) & 1) * 32 + (p_ & 31);               \
    async16(Wt + (size_t)(n0 + nl_) * K_DIM + (kt) + scol,                           \
            (ldsbase) + (row0) * 128 + sldsoff); } while (0)

#define LOAD_AF(ldsbase, MH)                                                         \
    _Pragma("unroll") for (int m_ = 0; m_ < 4; ++m_)                                 \
    _Pragma("unroll") for (int ks_ = 0; ks_ < 2; ++ks_)                              \
        afr[m_][ks_] = *(const bf16x8*)((ldsbase) + aRowB + (MH) * 8192 + m_ * 2048 + colsw[ks_]);

#define LOAD_BF(dst, ldsbase, NH)                                                    \
    _Pragma("unroll") for (int n_ = 0; n_ < 2; ++n_)                                 \
    _Pragma("unroll") for (int ks_ = 0; ks_ < 2; ++ks_)                              \
        dst[n_][ks_] = *(const bf16x8*)((ldsbase) + bRowB + (NH) * 16384 + n_ * 2048 + colsw[ks_]);

#define MFMA_Q(MH, NH, BF)                                                           \
    __builtin_amdgcn_s_setprio(1);                                                   \
    _Pragma("unroll") for (int m_ = 0; m_ < 4; ++m_)                                 \
    _Pragma("unroll") for (int n_ = 0; n_ < 2; ++n_)                                 \
    _Pragma("unroll") for (int ks_ = 0; ks_ < 2; ++ks_)                              \
        acc[(MH) * 4 + m_][(NH) * 2 + n_] = __builtin_amdgcn_mfma_f32_16x16x32_bf16( \
            afr[m_][ks_], BF[n_][ks_], acc[(MH) * 4 + m_][(NH) * 2 + n_], 0, 0, 0);  \
    __builtin_amdgcn_s_setprio(0);                                                   \
    __builtin_amdgcn_sched_barrier(0);

#define TILE_FULL(AC, BC, AO, BO, KT)                                                \
    LOAD_AF(AC, 0); LOAD_BF(b0f, BC, 0);                                             \
    STAGE_B(BO, 0, (KT) + 64); STAGE_B(BO, 64, (KT) + 64);                           \
    BARRIER(); MFMA_Q(0, 0, b0f); BARRIER();                                         \
    LOAD_BF(b1f, BC, 1);                                                             \
    STAGE_A(AO, 64, (KT) + 64); STAGE_A(AO, 192, (KT) + 64);                         \
    BARRIER(); MFMA_Q(0, 1, b1f); WAIT_VM(8); BARRIER();                             \
    LOAD_AF(AC, 1);                                                                  \
    STAGE_A(AC, 0, (KT) + 128); STAGE_A(AC, 128, (KT) + 128);                        \
    BARRIER(); MFMA_Q(1, 1, b1f); BARRIER();                                         \
    STAGE_B(BC, 128, (KT) + 128); STAGE_B(BC, 192, (KT) + 128);                      \
    BARRIER(); MFMA_Q(1, 0, b0f); WAIT_VM(6); BARRIER();

__global__ __launch_bounds__(512, 2) void gemm256_kernel(
    const __bf16* __restrict__ Xb, const __bf16* __restrict__ Wt,
    const float* __restrict__ bias, float* __restrict__ out) {
    extern __shared__ __align__(16) char smem[];
    const int tid  = threadIdx.x;
    const int lane = tid & 63;
    const int wave = tid >> 6;
    const int wr = wave >> 2;   // 0..1
    const int wn = wave & 3;    // 0..3

    const int bid = blockIdx.x;
    const int wg = (bid & 7) * 128 + (bid >> 3);   // XCD swizzle, 1024 % 8 == 0
    const int m0 = (wg >> 4) * 256;
    const int n0 = (wg & 15) * 256;

    char* A0 = smem;
    char* B0 = smem + 32768;
    char* A1 = smem + 65536;
    char* B1 = smem + 98304;

    // staging constants: thread covers chunk row srow, 16B group (tid&7)
    const int srow = tid >> 3;
    const int scol = ((tid & 7) ^ (srow & 7)) << 3;   // inverse-swizzled source col (elems)
    const int sldsoff = wave * 1024;                  // wave-uniform LDS offset in chunk

    // frag-read constants (row&7 == lane&7 for all frag rows)
    int colsw[2];
#pragma unroll
    for (int ks = 0; ks < 2; ++ks)
        colsw[ks] = ((ks * 32 + (lane >> 4) * 8) ^ ((lane & 7) * 8)) << 1;
    const int aRowB = (wr * 128 + (lane & 15)) * 128;
    const int bRowB = (wn * 32 + (lane & 15)) * 128;

    f32x4 acc[8][4] = {};
    bf16x8 afr[4][2], b0f[2][2], b1f[2][2];

    // ---- prologue: tile0 (4 HTs) + tile1 {A-HT0, B-HT1}; leave last 4 loads in flight
    STAGE_A(A0, 0, 0);    STAGE_A(A0, 128, 0);
    STAGE_B(B0, 0, 0);    STAGE_B(B0, 64, 0);
    STAGE_A(A0, 64, 0);   STAGE_A(A0, 192, 0);
    STAGE_B(B0, 128, 0);  STAGE_B(B0, 192, 0);
    STAGE_A(A1, 0, 64);   STAGE_A(A1, 128, 64);
    STAGE_B(B1, 128, 64); STAGE_B(B1, 192, 64);
    WAIT_VM(4);
    BARRIER();

    // ---- main loop: tiles 0..61 (stages reference tiles up to 63)
    for (int it = 0; it < 31; ++it) {
        const int kt = it * 128;
        TILE_FULL(A0, B0, A1, B1, kt);
        TILE_FULL(A1, B1, A0, B0, kt + 64);
    }

    // ---- tile 62 (buf0, kt=3968): stage only tile63's B-HT0 / A-HT1
    LOAD_AF(A0, 0); LOAD_BF(b0f, B0, 0);
    STAGE_B(B1, 0, 4032); STAGE_B(B1, 64, 4032);
    BARRIER(); MFMA_Q(0, 0, b0f); BARRIER();
    LOAD_BF(b1f, B0, 1);
    STAGE_A(A1, 64, 4032); STAGE_A(A1, 192, 4032);
    BARRIER(); MFMA_Q(0, 1, b1f); WAIT_VM(8); BARRIER();
    LOAD_AF(A0, 1);
    BARRIER(); MFMA_Q(1, 1, b1f); BARRIER();
    BARRIER(); MFMA_Q(1, 0, b0f); WAIT_VM(2); BARRIER();

    // ---- tile 63 (buf1, kt=4032): no stages; drain remaining before q3 reads
    LOAD_AF(A1, 0); LOAD_BF(b0f, B1, 0);
    BARRIER(); MFMA_Q(0, 0, b0f); BARRIER();
    LOAD_BF(b1f, B1, 1);
    BARRIER(); MFMA_Q(0, 1, b1f); WAIT_VM(0); BARRIER();
    LOAD_AF(A1, 1);
    BARRIER(); MFMA_Q(1, 1, b1f); BARRIER();
    MFMA_Q(1, 0, b0f);

    // ---- epilogue: C/D map col=lane&15, row=(lane>>4)*4+j; nontemporal out stream
#pragma unroll
    for (int mh = 0; mh < 2; ++mh)
#pragma unroll
        for (int m = 0; m < 4; ++m) {
            const int gr = m0 + wr * 128 + mh * 64 + m * 16 + (lane >> 4) * 4;
#pragma unroll
            for (int nh = 0; nh < 2; ++nh)
#pragma unroll
                for (int n = 0; n < 2; ++n) {
                    const int gc = n0 + wn * 64 + nh * 32 + n * 16 + (lane & 15);
                    const float bv = bias[gc];
                    const f32x4 a = acc[mh * 4 + m][nh * 2 + n];
#pragma unroll
                    for (int j = 0; j < 4; ++j)
                        __builtin_nontemporal_store(a[j] + bv,
                            &out[(size_t)(gr + j) * N_DIM + gc]);
                }
        }
}

extern "C" void kernel_launch(void* const* d_in, const int* in_sizes, int n_in,
                              void* d_out, int out_size, void* d_ws, size_t ws_size,
                              hipStream_t stream) {
    const float* x    = (const float*)d_in[0];
    const float* W    = (const float*)d_in[1];
    const float* bias = (const float*)d_in[2];
    const float* lA   = (const float*)d_in[3];
    const float* lB   = (const float*)d_in[4];
    float* out = (float*)d_out;

    __bf16* Xb = (__bf16*)d_ws;
    __bf16* Wt = (__bf16*)((char*)d_ws + (size_t)M_DIM * K_DIM * 2);

    cast_x_kernel<<<2048, 256, 0, stream>>>(x, Xb, (size_t)M_DIM * K_DIM);
    prep_w_kernel<<<dim3(N_DIM / 32, K_DIM / 32), dim3(32, 8), 0, stream>>>(W, lA, lB, Wt);

    (void)hipFuncSetAttribute((const void*)gemm256_kernel,
                              hipFuncAttributeMaxDynamicSharedMemorySize, 131072);
    gemm256_kernel<<<1024, 512, 131072, stream>>>(Xb, Wt, bias, out);
}